// Round 1
// baseline (73.706 us; speedup 1.0000x reference)
//
#include <hip/hip_runtime.h>
#include <stdint.h>
#include <math.h>

typedef __attribute__((ext_vector_type(8))) short short8;
typedef __attribute__((ext_vector_type(16))) float f32x16;

#define DEVI static __device__ __forceinline__

constexpr int D = 256;          // feature dim
constexpr int MT = 128;         // m-chunk rows
constexpr int KT = 128;         // k-tile cols
constexpr int NCHUNK = 4;       // 512 / MT

constexpr int ZBUF_BYTES = MT * D * 2;   // 65536
constexpr int EBUF_BYTES = KT * D * 2;   // 65536
constexpr int OFF_EBUF  = ZBUF_BYTES;
constexpr int OFF_ZTERM = ZBUF_BYTES + EBUF_BYTES;
constexpr int OFF_ETERM = OFF_ZTERM + MT * 4;
constexpr int OFF_PMAX  = OFF_ETERM + KT * 4;
constexpr int OFF_PSUM  = OFF_PMAX + 2 * KT * 4;
constexpr int SMEM_BYTES = OFF_PSUM + 2 * KT * 4;  // 134144

DEVI unsigned int f2bf(float f) {
  // round-to-nearest-even f32 -> bf16 bits (inputs are finite)
  unsigned int u = __float_as_uint(f);
  return (u + 0x7fffu + ((u >> 16) & 1u)) >> 16;
}

DEVI float shflx(float v, int m) { return __shfl_xor(v, m, 64); }

// Stage a [128 rows x 256 cols] f32 tile into LDS as bf16 (row stride 512B,
// XOR-swizzled) and write term[row] = -0.5*a*||row||^2 (norm from f32 data,
// pre-scale). Each of 8 waves stages 16 rows, 2 rows per pass
// (lanes 0-31 -> row p*2, lanes 32-63 -> row p*2+1), 8 floats per lane.
DEVI void stage_tile(const float* __restrict__ src, char* __restrict__ dst,
                     float* __restrict__ term, float storescale, float a,
                     int wid, int l31, int hi) {
#pragma unroll
  for (int p = 0; p < 8; ++p) {
    int crow = wid * 16 + p * 2 + hi;
    const float* s = src + (size_t)crow * D + l31 * 8;
    float4 x0 = *(const float4*)(s);
    float4 x1 = *(const float4*)(s + 4);
    float sq = x0.x * x0.x + x0.y * x0.y + x0.z * x0.z + x0.w * x0.w +
               x1.x * x1.x + x1.y * x1.y + x1.z * x1.z + x1.w * x1.w;
    // reduce over the 32 lanes of this half-wave (xor masks < 32 stay in-half)
    sq += shflx(sq, 1);  sq += shflx(sq, 2);  sq += shflx(sq, 4);
    sq += shflx(sq, 8);  sq += shflx(sq, 16);
    unsigned int w0 = f2bf(x0.x * storescale) | (f2bf(x0.y * storescale) << 16);
    unsigned int w1 = f2bf(x0.z * storescale) | (f2bf(x0.w * storescale) << 16);
    unsigned int w2 = f2bf(x1.x * storescale) | (f2bf(x1.y * storescale) << 16);
    unsigned int w3 = f2bf(x1.z * storescale) | (f2bf(x1.w * storescale) << 16);
    int byte = crow * 512 + l31 * 16;
    byte ^= (crow & 7) << 4;  // T2 bank-conflict swizzle (16B granules)
    uint4 pk; pk.x = w0; pk.y = w1; pk.z = w2; pk.w = w3;
    *(uint4*)(dst + byte) = pk;
    if (l31 == 0) term[crow] = -0.5f * a * sq;
  }
}

// Grid: 512 blocks = 128 b-blocks x 4 k-tiles; 512 threads (8 waves).
// Each block computes, for its 128 codebook columns, the LSE over all 512
// z-rows of its b-block, then writes sum_k LSE to partial[blockIdx.x].
__global__ __launch_bounds__(512, 1)
void lse_main(const float* __restrict__ z, const float* __restrict__ e,
              const float* __restrict__ lsp, float* __restrict__ partial) {
  extern __shared__ char smem[];
  char*  zbuf  = smem;
  char*  ebuf  = smem + OFF_EBUF;
  float* zterm = (float*)(smem + OFF_ZTERM);
  float* eterm = (float*)(smem + OFF_ETERM);
  float* pmaxb = (float*)(smem + OFF_PMAX);   // [2][128]
  float* psumb = (float*)(smem + OFF_PSUM);   // [2][128]

  const int tid  = threadIdx.x;
  const int wid  = tid >> 6;
  const int lane = tid & 63;
  const int hi   = lane >> 5;
  const int l31  = lane & 31;
  const int bx = blockIdx.x;
  const int b  = bx >> 2;
  const int kt = bx & 3;

  const float a = __expf(-2.0f * lsp[0]);  // alpha*dist = a*(z.e) - a/2(|z|^2+|e|^2)

  // e tile: store bf16(a*e); eterm from unscaled f32 e
  stage_tile(e + (size_t)(kt * KT) * D, ebuf, eterm, a, a, wid, l31, hi);

  const int wr = wid >> 2;  // 0..1 : which 64 m-rows
  const int wc = wid & 3;   // 0..3 : which 32 k-cols

  float rmax = -1e30f, rsum = 0.0f;  // running LSE state for column 'tid' (tid<128)

  for (int mc = 0; mc < NCHUNK; ++mc) {
    stage_tile(z + ((size_t)b * 512 + mc * MT) * D, zbuf, zterm, 1.0f, a, wid, l31, hi);
    __syncthreads();  // staging visible (covers e-buf on first iteration too)

    f32x16 acc0, acc1;
#pragma unroll
    for (int i = 0; i < 16; ++i) { acc0[i] = 0.0f; acc1[i] = 0.0f; }

#pragma unroll
    for (int ks = 0; ks < 16; ++ks) {   // K = 256, 16 per step
      const int kb = ks * 32 + hi * 16; // byte offset: k elem = ks*16 + hi*8
      short8 fa0, fa1, fb;
      {
        int row = wr * 64 + l31;
        int byte = row * 512 + kb; byte ^= (row & 7) << 4;
        fa0 = *(const short8*)(zbuf + byte);
      }
      {
        int row = wr * 64 + 32 + l31;
        int byte = row * 512 + kb; byte ^= (row & 7) << 4;
        fa1 = *(const short8*)(zbuf + byte);
      }
      {
        int row = wc * 32 + l31;
        int byte = row * 512 + kb; byte ^= (row & 7) << 4;
        fb = *(const short8*)(ebuf + byte);
      }
      acc0 = __builtin_amdgcn_mfma_f32_32x32x16_bf16(fa0, fb, acc0, 0, 0, 0);
      acc1 = __builtin_amdgcn_mfma_f32_32x32x16_bf16(fa1, fb, acc1, 0, 0, 0);
    }

    // epilogue: S = acc + zterm[row]; per-column (over this wave's 64 rows)
    // max and sum(exp). C layout: col = l31, row = (r&3) + 8*(r>>2) + 4*hi (+32*mi)
    float zt[32];
#pragma unroll
    for (int mi = 0; mi < 2; ++mi)
#pragma unroll
      for (int r = 0; r < 16; ++r)
        zt[mi * 16 + r] = zterm[wr * 64 + mi * 32 + (r & 3) + 8 * (r >> 2) + 4 * hi];

    float v[32];
#pragma unroll
    for (int r = 0; r < 16; ++r) {
      v[r]      = acc0[r] + zt[r];
      v[16 + r] = acc1[r] + zt[16 + r];
    }
    float mx = v[0];
#pragma unroll
    for (int i = 1; i < 32; ++i) mx = fmaxf(mx, v[i]);
    mx = fmaxf(mx, shflx(mx, 32));  // combine the two hi-halves (other 32 rows)
    float sme = 0.0f;
#pragma unroll
    for (int i = 0; i < 32; ++i) sme += __expf(v[i] - mx);
    sme += shflx(sme, 32);
    if (hi == 0) {
      int col = wc * 32 + l31;
      pmaxb[wr * KT + col] = mx;
      psumb[wr * KT + col] = sme;
    }
    __syncthreads();  // partials visible; all LDS frag reads done

    if (tid < KT) {  // merge both wr-halves into running state for column tid
      float p0 = pmaxb[tid], p1 = pmaxb[KT + tid];
      float s0 = psumb[tid], s1 = psumb[KT + tid];
      float nm = fmaxf(rmax, fmaxf(p0, p1));
      rsum = rsum * __expf(rmax - nm) + s0 * __expf(p0 - nm) + s1 * __expf(p1 - nm);
      rmax = nm;
    }
    // no extra barrier: next epilogue's pmax writes are ordered after the next
    // __syncthreads(); staging only touches zbuf/zterm (last read before S2).
  }

  if (tid < KT) {
    float lse = rmax + logf(rsum) + eterm[tid];
    pmaxb[tid] = lse;  // only thread 'tid' touches slot tid in both phases
  }
  __syncthreads();
  if (tid == 0) {
    float s = 0.0f;
    for (int i = 0; i < KT; ++i) s += pmaxb[i];
    partial[bx] = s;
  }
}

__global__ void finalk(const float* __restrict__ partial,
                       const float* __restrict__ lsp, float* __restrict__ out) {
  __shared__ float sh[512];
  int t = threadIdx.x;
  sh[t] = partial[t];
  __syncthreads();
  for (int s = 256; s > 0; s >>= 1) {
    if (t < s) sh[t] += sh[t + s];
    __syncthreads();
  }
  if (t == 0) {
    float ls = lsp[0];
    // loss = -sum(LSE)/ (B*M) + 0.5*D*(2*ls - 1) + log(M)
    out[0] = -sh[0] / 65536.0f + 128.0f * (2.0f * ls - 1.0f) + logf(512.0f);
  }
}

extern "C" void kernel_launch(void* const* d_in, const int* in_sizes, int n_in,
                              void* d_out, int out_size, void* d_ws, size_t ws_size,
                              hipStream_t stream) {
  const float* z   = (const float*)d_in[0];
  const float* e   = (const float*)d_in[1];
  const float* lsp = (const float*)d_in[2];
  float* out     = (float*)d_out;
  float* partial = (float*)d_ws;  // 512 floats, fully rewritten each call

  hipFuncSetAttribute(reinterpret_cast<const void*>(lse_main),
                      hipFuncAttributeMaxDynamicSharedMemorySize, SMEM_BYTES);
  lse_main<<<dim3(512), dim3(512), SMEM_BYTES, stream>>>(z, e, lsp, partial);
  finalk<<<dim3(1), dim3(512), 0, stream>>>(partial, lsp, out);
}